// Round 10
// baseline (79.127 us; speedup 1.0000x reference)
//
#include <hip/hip_runtime.h>
#include <hip/hip_bf16.h>
#include <stdint.h>
#include <stddef.h>

// Problem constants
#define B_    2
#define NREF  3
#define FDIM  256
#define HW    4096
#define DCLS  10
#define RTOT  12288          // NREF*HW reference pixels per batch
#define TT    128            // target pixels per block (4 waves x 32t)
#define RR    32             // reference pixels per chunk
#define RS    16             // r-axis split across blocks
#define RPB   768            // RTOT/RS
#define NCH   24             // RPB/RR
#define NPIX  8192           // B_*HW
#define LOG2E 1.44269504f
#define C0f   (-144.269504f)  // -100*LOG2E; QK acc init so acc = sim*log2e - 100*log2e

typedef __attribute__((ext_vector_type(8))) short bf16x8;
typedef __attribute__((ext_vector_type(4))) float f32x4;
typedef __attribute__((ext_vector_type(4))) unsigned int u32x4;

__device__ __forceinline__ unsigned short f2bf(float x) {
  union { float f; unsigned u; } v; v.f = x;
  unsigned r = v.u + 0x7fffu + ((v.u >> 16) & 1u);   // RNE
  return (unsigned short)(r >> 16);
}
__device__ __forceinline__ unsigned pk2(float a, float b) {
  return (unsigned)f2bf(a) | ((unsigned)f2bf(b) << 16);
}
// single-instruction packed f32->bf16 (RNE), gfx950
__device__ __forceinline__ unsigned cvtpk(float a, float b) {
  unsigned r;
  asm("v_cvt_pk_bf16_f32 %0, %1, %2" : "=v"(r) : "v"(a), "v"(b));
  return r;
}
// async global->LDS, 16B per lane; LDS dest is wave-uniform base + lane*16
__device__ __forceinline__ void async16(const void* g, void* l) {
  __builtin_amdgcn_global_load_lds(
      (const __attribute__((address_space(1))) void*)g,
      (__attribute__((address_space(3))) void*)l, 16, 0, 0);
}
// one-hot pair: low/high 16-bit bf16 1.0 where label byte matches d=l15
__device__ __forceinline__ unsigned oh2(unsigned word, int d) {
  return ((word & 255u) == (unsigned)d ? 0x3F80u : 0u) |
         (((word >> 8) & 255u) == (unsigned)d ? 0x3F800000u : 0u);
}

// ---------------- kernel 1: fused prep (transpose+convert) + label extract ----------------
// blocks [0,256): ref/tgt -> bf16 rows of 512B with XOR swizzle baked per row.
// ref rows pre-scaled by LOG2E (QK comes out in log2 units; -100*log2e via acc init).
__global__ __launch_bounds__(256) void k_pre(const float* __restrict__ ref,
                                             const float* __restrict__ tgt,
                                             const float* __restrict__ rl,
                                             char* __restrict__ outb,
                                             unsigned char* __restrict__ lab8) {
  const int tid = threadIdx.x;
  if (blockIdx.x < 256) {
    const int row = blockIdx.x * 128 + (tid & 127);   // row 0..32767
    const int half = tid >> 7;
    const float* src;
    float scl;
    if (row < B_ * RTOT) {
      const int b = row / RTOT, rr2 = row % RTOT;
      src = ref + ((size_t)(b * NREF + (rr2 >> 12)) * FDIM) * HW + (rr2 & 4095);
      scl = LOG2E;
    } else {
      const int r2 = row - B_ * RTOT;
      src = tgt + ((size_t)(r2 >> 12) * FDIM) * HW + (r2 & 4095);
      scl = 1.0f;
    }
    char* dst = outb + (size_t)row * 512;
    const int sw = (row & 7) << 4;
    for (int ci = 0; ci < 16; ++ci) {
      const int c16 = half * 16 + ci;
      float v[8];
#pragma unroll
      for (int j = 0; j < 8; ++j) v[j] = src[(size_t)(c16 * 8 + j) * HW] * scl;
      u32x4 u;
      u[0] = pk2(v[0], v[1]); u[1] = pk2(v[2], v[3]);
      u[2] = pk2(v[4], v[5]); u[3] = pk2(v[6], v[7]);
      *(u32x4*)(dst + ((c16 * 16) ^ sw)) = u;
    }
  } else {
    const int idx = (blockIdx.x - 256) * 256 + tid;   // < 24576
    if (idx >= B_ * RTOT) return;
    const int b = idx / RTOT, r = idx % RTOT;
    const float* p = rl + ((size_t)((b * NREF + (r >> 12)) * DCLS)) * HW + (r & 4095);
    int v = 0;
#pragma unroll
    for (int d = 1; d < DCLS; ++d)
      if (p[(size_t)d * HW] > 0.5f) v = d;
    lab8[idx] = (unsigned char)v;
  }
}

// ---------------- kernel 2: fused QK-softmax-PV (16x16x32; 32r x 32t waves) ----------------
// grid = RS(16) * 32(tblocks) * B_(2) = 1024 blocks of 256 threads, 4 blocks/CU.
// All 4 waves share the chunk's 32 r; wave w owns t in [tb*128+w*32, +32) exclusively
// -> no cross-wave epilogue reduction. Blocks sharing an A-slice: bid ≡ rs (mod 16)
// -> fixed XCD (bid%8 = rs%8), slice stays L2-resident.
__global__ __launch_bounds__(256, 4) void k_main(const char* __restrict__ refb,
                                                 const char* __restrict__ tgtb,
                                                 const unsigned char* __restrict__ lab8,
                                                 float* __restrict__ pred) {
  __shared__ __align__(16) char Ash[2][RR * 512];   // double-buffered ref chunk, 32 KB

  const int tid = threadIdx.x;
  const int lane = tid & 63;
  const int w = tid >> 6;                // wave 0..3 -> t-slice
  const int l15 = lane & 15, l4 = lane >> 4;
  const int swz = (l15 & 7) << 4;

  const int bid = blockIdx.x;
  const int rs = bid & 15;
  const int tb = (bid >> 4) & 31;
  const int b  = bid >> 9;

  // ---- B fragments in registers: wave's 32 t x full K=256 (64 VGPR) ----
  bf16x8 bfr[2][8];
  {
    const char* base = tgtb + ((size_t)(b * HW + tb * TT + w * 32)) * 512;
#pragma unroll
    for (int nt = 0; nt < 2; ++nt) {
      const char* rp = base + (size_t)((nt * 16 + l15) * 512);
#pragma unroll
      for (int ks = 0; ks < 8; ++ks)
        bfr[nt][ks] = *(const bf16x8*)(rp + ((ks * 64 + l4 * 16) ^ swz));
    }
  }

  f32x4 pacc[2];
  pacc[0] = f32x4{0.f, 0.f, 0.f, 0.f};
  pacc[1] = f32x4{0.f, 0.f, 0.f, 0.f};

  const char* Asrc = refb + ((size_t)(b * RTOT + rs * RPB)) * 512;

  // precomputed A-read base pointers (buf0); buf1 via +16384 immediate
  const char* ap00 = &Ash[0][( 0 + l15) * 512 + ((     l4 * 16) ^ swz)];
  const char* ap01 = &Ash[0][( 0 + l15) * 512 + ((64 + l4 * 16) ^ swz)];
  const char* ap10 = &Ash[0][(16 + l15) * 512 + ((     l4 * 16) ^ swz)];
  const char* ap11 = &Ash[0][(16 + l15) * 512 + ((64 + l4 * 16) ^ swz)];

  // stage chunk (32 rows x 512B = 16 segs of 1 KB, 4 per wave)
  auto stage = [&](const char* s, char* dbuf) {
#pragma unroll
    for (int i2 = 0; i2 < 4; ++i2) {
      const int seg = i2 * 4 + w;
      async16(s + seg * 1024 + lane * 16, dbuf + seg * 1024);
    }
  };
  // QK^T of one chunk: 32 MFMA/wave; acc init = C0f (exp bias in the C operand)
  auto qk = [&](f32x4 (&acc)[2][2], const int OFS) {
#pragma unroll
    for (int i2 = 0; i2 < 2; ++i2)
#pragma unroll
      for (int j = 0; j < 2; ++j) acc[i2][j] = f32x4{C0f, C0f, C0f, C0f};
    __builtin_amdgcn_s_setprio(1);
#pragma unroll
    for (int ks = 0; ks < 8; ++ks) {
      const int ko = OFS + (ks >> 1) * 128;
      const bf16x8 af0 = *(const bf16x8*)(((ks & 1) ? ap01 : ap00) + ko);
      const bf16x8 af1 = *(const bf16x8*)(((ks & 1) ? ap11 : ap10) + ko);
#pragma unroll
      for (int nt = 0; nt < 2; ++nt)
        acc[0][nt] = __builtin_amdgcn_mfma_f32_16x16x32_bf16(
            af0, bfr[nt][ks], acc[0][nt], 0, 0, 0);
#pragma unroll
      for (int nt = 0; nt < 2; ++nt)
        acc[1][nt] = __builtin_amdgcn_mfma_f32_16x16x32_bf16(
            af1, bfr[nt][ks], acc[1][nt], 0, 0, 0);
    }
    __builtin_amdgcn_s_setprio(0);
  };
  // exp2 + pack + PV (wave-local; acc reg layout IS the PV B-frag layout)
  auto pv = [&](const f32x4 (&acc)[2][2], unsigned la, unsigned lb2) {
    union { bf16x8 v; unsigned u[4]; } lf;
    lf.u[0] = oh2(la, l15);        lf.u[1] = oh2(la >> 16, l15);
    lf.u[2] = oh2(lb2, l15);       lf.u[3] = oh2(lb2 >> 16, l15);
#pragma unroll
    for (int nt = 0; nt < 2; ++nt) {
      const f32x4 a0 = acc[0][nt], a1 = acc[1][nt];
      float p0 = __builtin_amdgcn_exp2f(a0[0]);
      float p1 = __builtin_amdgcn_exp2f(a0[1]);
      float p2 = __builtin_amdgcn_exp2f(a0[2]);
      float p3 = __builtin_amdgcn_exp2f(a0[3]);
      float p4 = __builtin_amdgcn_exp2f(a1[0]);
      float p5 = __builtin_amdgcn_exp2f(a1[1]);
      float p6 = __builtin_amdgcn_exp2f(a1[2]);
      float p7 = __builtin_amdgcn_exp2f(a1[3]);
      union { bf16x8 v; unsigned u[4]; } pf;
      pf.u[0] = cvtpk(p0, p1); pf.u[1] = cvtpk(p2, p3);
      pf.u[2] = cvtpk(p4, p5); pf.u[3] = cvtpk(p6, p7);
      pacc[nt] = __builtin_amdgcn_mfma_f32_16x16x32_bf16(lf.v, pf.v, pacc[nt], 0, 0, 0);
    }
  };

  f32x4 acc[2][2];
  const unsigned char* lbp = lab8 + b * RTOT + rs * RPB + l4 * 4;
  const char* Acur = Asrc + 2 * (RR * 512);   // global source of chunk 2

  // prologue: labels(0); stage(0)->buf0; drain; stage(1)->buf1; qk(0)
  unsigned la_p = *(const unsigned*)lbp;
  unsigned lb_p = *(const unsigned*)(lbp + 16);
  lbp += RR;
  stage(Asrc, &Ash[0][0]);
  __syncthreads();
  stage(Asrc + RR * 512, &Ash[1][0]);
  qk(acc, 0);

#pragma unroll 1
  for (int i = 0; i < 11; ++i) {
    {   // chunk c=1+2i (odd, buf1); stage c+1 -> buf0; pv(c-1) fills qk ramp
      const unsigned la_n = *(const unsigned*)lbp;
      const unsigned lb_n = *(const unsigned*)(lbp + 16);
      lbp += RR;
      __syncthreads();                   // drain DMA(c); readers of buf0 done
      stage(Acur, &Ash[0][0]); Acur += RR * 512;
      pv(acc, la_p, lb_p);               // chunk c-1 (regs only)
      qk(acc, 16384);                    // chunk c from buf1
      la_p = la_n; lb_p = lb_n;
    }
    {   // chunk c=2+2i (even, buf0); stage c+1 -> buf1
      const unsigned la_n = *(const unsigned*)lbp;
      const unsigned lb_n = *(const unsigned*)(lbp + 16);
      lbp += RR;
      __syncthreads();
      stage(Acur, &Ash[1][0]); Acur += RR * 512;
      pv(acc, la_p, lb_p);               // chunk c-1
      qk(acc, 0);                        // chunk c from buf0
      la_p = la_n; lb_p = lb_n;
    }
  }
  {   // chunk 23 (odd, buf1): no stage; then final pv(23)
    const unsigned la_n = *(const unsigned*)lbp;   // labels(23)
    const unsigned lb_n = *(const unsigned*)(lbp + 16);
    __syncthreads();                     // drain DMA(23)
    pv(acc, la_p, lb_p);                 // chunk 22
    qk(acc, 16384);                      // chunk 23
    pv(acc, la_n, lb_n);                 // chunk 23
  }

  // ---- epilogue: each wave owns its 32-t slice; direct global write ----
#pragma unroll
  for (int nt = 0; nt < 2; ++nt) {
    const int t = w * 32 + nt * 16 + l15;
    const size_t o = (((size_t)(rs * B_ + b)) * HW + (size_t)tb * TT + t) * 16 + l4 * 4;
    *(f32x4*)&pred[o] = pacc[nt];
  }
}

// ---------------- kernel 3: per-pixel loss terms + wave reduce ----------------
__global__ __launch_bounds__(64) void k_epi(const float* __restrict__ pred,
                                            const int* __restrict__ tl,
                                            float* __restrict__ red) {
  const int idx = blockIdx.x * 64 + threadIdx.x;   // < 8192
  const int b = idx >> 12, t = idx & 4095;
  union { f32x4 v[3]; float f[12]; } S;
  S.v[0] = f32x4{0.f, 0.f, 0.f, 0.f};
  S.v[1] = f32x4{0.f, 0.f, 0.f, 0.f};
  S.v[2] = f32x4{0.f, 0.f, 0.f, 0.f};
#pragma unroll
  for (int r = 0; r < RS; ++r) {
    const f32x4* p = (const f32x4*)&pred[(((size_t)(r * B_ + b)) * HW + t) * 16];
    S.v[0] += p[0]; S.v[1] += p[1]; S.v[2] += p[2];
  }
  float T = 0.f;
#pragma unroll
  for (int d = 0; d < DCLS; ++d) T += S.f[d];
  const float inv = 1.f / T;
  const int lb = tl[idx];
  float se = 0.f, zt = 0.f;
#pragma unroll
  for (int d = 0; d < DCLS; ++d) {
    const float z = S.f[d] * inv;      // pred prob in [0,1]
    se += __expf(z);
    if (d == lb) zt = z;
  }
  const float logpt = zt - __logf(se);
  const float pt = __expf(zt) / se;
  const float focal = sqrtf(fmaxf(1.f - pt, 0.f));   // gamma = 0.5

  float lp = logpt, fo = focal;
#pragma unroll
  for (int off = 32; off; off >>= 1) {
    lp += __shfl_down(lp, off);
    fo += __shfl_down(fo, off);
  }
  if (threadIdx.x == 0) {
    red[blockIdx.x * 2 + 0] = lp;
    red[blockIdx.x * 2 + 1] = fo;
  }
}

// ---------------- kernel 4: final scalar ----------------
__global__ void k_fin(const float* __restrict__ red, float* __restrict__ out) {
  const int tid = threadIdx.x;   // 64; 128 block-pairs
  float lp = red[tid * 2]       + red[(tid + 64) * 2];
  float fo = red[tid * 2 + 1]   + red[(tid + 64) * 2 + 1];
#pragma unroll
  for (int off = 32; off; off >>= 1) {
    lp += __shfl_down(lp, off);
    fo += __shfl_down(fo, off);
  }
  if (tid == 0) {
    const float ce = -lp / (float)NPIX;       // ce = -mean(log_pt)
    out[0] = ce * (fo / (float)NPIX);         // loss = ce * mean(focal)
  }
}

extern "C" void kernel_launch(void* const* d_in, const int* in_sizes, int n_in,
                              void* d_out, int out_size, void* d_ws, size_t ws_size,
                              hipStream_t stream)
{
  const float* ref  = (const float*)d_in[0];
  const float* tgt  = (const float*)d_in[1];
  const float* rl   = (const float*)d_in[2];
  const int*   tlab = (const int*)d_in[3];
  float* out = (float*)d_out;

  char* ws = (char*)d_ws;
  char* refb = ws;                                    // 32768 rows * 512 B = 16 MB (ref + tgt)
  char* tgtb = ws + (size_t)24576 * 512;              // tgt rows start at 24576
  unsigned char* lab8 = (unsigned char*)(ws + 16777216);          // 24 KB (pad 32 KB)
  float* pred = (float*)(ws + 16777216 + 32768);                  // 8 MB (RS*B*HW*16 f32)
  float* red  = (float*)(ws + 16777216 + 32768 + 8388608);        // 1 KB

  k_pre<<<352, 256, 0, stream>>>(ref, tgt, rl, refb, lab8);
  k_main<<<1024, 256, 0, stream>>>(refb, tgtb, lab8, pred);
  k_epi<<<128, 64, 0, stream>>>(pred, tlab, red);
  k_fin<<<1, 64, 0, stream>>>(red, out);
}

// Round 12
// 59.772 us; speedup vs baseline: 1.3238x; 1.3238x over previous
//
#include <hip/hip_runtime.h>
#include <hip/hip_bf16.h>
#include <stdint.h>
#include <stddef.h>

// Problem constants
#define B_    2
#define NREF  3
#define FDIM  256
#define HW    4096
#define DCLS  10
#define RTOT  12288          // NREF*HW reference pixels per batch
#define TT    128            // target pixels per block (4 waves)
#define RR    64             // reference pixels per chunk
#define RS    8              // r-axis split across blocks
#define RPB   1536           // RTOT/RS
#define NCH   24             // RPB/RR
#define NPIX  8192           // B_*HW
#define LOG2E 1.44269504f
#define C0f   (-144.269504f)  // -100*LOG2E; QK acc init so acc = sim*log2e - 100*log2e

typedef __attribute__((ext_vector_type(8))) short bf16x8;
typedef __attribute__((ext_vector_type(4))) float f32x4;
typedef __attribute__((ext_vector_type(4))) unsigned int u32x4;

__device__ __forceinline__ unsigned short f2bf(float x) {
  union { float f; unsigned u; } v; v.f = x;
  unsigned r = v.u + 0x7fffu + ((v.u >> 16) & 1u);   // RNE
  return (unsigned short)(r >> 16);
}
__device__ __forceinline__ unsigned pk2(float a, float b) {
  return (unsigned)f2bf(a) | ((unsigned)f2bf(b) << 16);
}
// single-instruction packed f32->bf16 (RNE), gfx950
__device__ __forceinline__ unsigned cvtpk(float a, float b) {
  unsigned r;
  asm("v_cvt_pk_bf16_f32 %0, %1, %2" : "=v"(r) : "v"(a), "v"(b));
  return r;
}
// async global->LDS, 16B per lane; LDS dest is wave-uniform base + lane*16
__device__ __forceinline__ void async16(const void* g, void* l) {
  __builtin_amdgcn_global_load_lds(
      (const __attribute__((address_space(1))) void*)g,
      (__attribute__((address_space(3))) void*)l, 16, 0, 0);
}
// one-hot pair: low/high 16-bit bf16 1.0 where label byte matches d=l15
__device__ __forceinline__ unsigned oh2(unsigned word, int d) {
  return ((word & 255u) == (unsigned)d ? 0x3F80u : 0u) |
         (((word >> 8) & 255u) == (unsigned)d ? 0x3F800000u : 0u);
}

// ---------------- kernel 1: fused prep (transpose+convert) + label extract ----------------
// blocks [0,512): ref/tgt -> bf16 rows of 512B with XOR swizzle baked per row.
// Each block: 64 rows x 4 quarter-rows (256 thr); 512 blocks cover all 32768 rows
// (round-11 bug: 1024 blocks wrote 2x past the buffer -> abort). ~2 blocks/CU... use
// 64-row blocks for 2x the blocks of round 9's version and shorter per-thread chains.
// blocks [512,608): one-hot -> u8 labels.
__global__ __launch_bounds__(256) void k_pre(const float* __restrict__ ref,
                                             const float* __restrict__ tgt,
                                             const float* __restrict__ rl,
                                             char* __restrict__ outb,
                                             unsigned char* __restrict__ lab8) {
  const int tid = threadIdx.x;
  if (blockIdx.x < 512) {
    const int row = blockIdx.x * 64 + (tid & 63);     // row 0..32767 (lane-coalesced)
    const int q = tid >> 6;                           // quarter 0..3
    const float* src;
    float scl;
    if (row < B_ * RTOT) {
      const int b = row / RTOT, rr2 = row % RTOT;
      src = ref + ((size_t)(b * NREF + (rr2 >> 12)) * FDIM) * HW + (rr2 & 4095);
      scl = LOG2E;
    } else {
      const int r2 = row - B_ * RTOT;
      src = tgt + ((size_t)(r2 >> 12) * FDIM) * HW + (r2 & 4095);
      scl = 1.0f;
    }
    char* dst = outb + (size_t)row * 512;
    const int sw = (row & 7) << 4;
#pragma unroll
    for (int ci = 0; ci < 4; ++ci) {
      const int c16 = q * 4 + ci;
      float v[8];
#pragma unroll
      for (int j = 0; j < 8; ++j) v[j] = src[(size_t)(c16 * 8 + j) * HW] * scl;
      u32x4 u;
      u[0] = pk2(v[0], v[1]); u[1] = pk2(v[2], v[3]);
      u[2] = pk2(v[4], v[5]); u[3] = pk2(v[6], v[7]);
      *(u32x4*)(dst + ((c16 * 16) ^ sw)) = u;
    }
  } else {
    const int idx = (blockIdx.x - 512) * 256 + tid;   // < 24576
    if (idx >= B_ * RTOT) return;
    const int b = idx / RTOT, r = idx % RTOT;
    const float* p = rl + ((size_t)((b * NREF + (r >> 12)) * DCLS)) * HW + (r & 4095);
    int v = 0;
#pragma unroll
    for (int d = 1; d < DCLS; ++d)
      if (p[(size_t)d * HW] > 0.5f) v = d;
    lab8[idx] = (unsigned char)v;
  }
}

// ---------------- kernel 2: fused QK-softmax-PV (16x16x32, pv deferred one step) ----------------
// grid = RS(8) * 32(tblocks) * B_(2) = 512 blocks of 256 threads, 2 blocks/CU.
// Per step: barrier; load labels(c) [consumed next step -> 1 chunk old at next
// barrier's vmcnt(0) drain]; stage(c+1); pv(c-1) [regs only]; qk(c).
// All vmem pending at any barrier is >= 1 chunk old -> drain is instant.
__global__ __launch_bounds__(256, 2) void k_main(const char* __restrict__ refb,
                                                 const char* __restrict__ tgtb,
                                                 const unsigned char* __restrict__ lab8,
                                                 float* __restrict__ pred) {
  __shared__ __align__(16) char Ash[2][RR * 512];   // double-buffered ref chunk, 64 KB

  const int tid = threadIdx.x;
  const int lane = tid & 63;
  const int w = tid >> 6;                // wave 0..3
  const int l15 = lane & 15, l4 = lane >> 4;
  const int rh = w >> 1, th = w & 1;     // wave sub-tile: 32r x 64t
  const int swz = (l15 & 7) << 4;

  const int bid = blockIdx.x;
  const int rs = bid & 7;
  const int tb = (bid >> 3) & 31;
  const int b  = bid >> 8;

  // ---- B fragments in registers: wave's 64 t x full K=256 (128 VGPR) ----
  bf16x8 bfr[4][8];
  {
    const char* base = tgtb + ((size_t)(b * HW + tb * TT + th * 64)) * 512;
#pragma unroll
    for (int nt = 0; nt < 4; ++nt) {
      const char* rp = base + (size_t)((nt * 16 + l15) * 512);
#pragma unroll
      for (int ks = 0; ks < 8; ++ks)
        bfr[nt][ks] = *(const bf16x8*)(rp + ((ks * 64 + l4 * 16) ^ swz));
    }
  }

  f32x4 pacc[4];
#pragma unroll
  for (int i = 0; i < 4; ++i) pacc[i] = f32x4{0.f, 0.f, 0.f, 0.f};

  const char* Asrc = refb + ((size_t)(b * RTOT + rs * RPB)) * 512;

  // precomputed A-read base pointers (buf0); buf1 reached via +32768 immediate
  const char* ap00 = &Ash[0][(rh * 32 +  0 + l15) * 512 + ((     l4 * 16) ^ swz)];
  const char* ap01 = &Ash[0][(rh * 32 +  0 + l15) * 512 + ((64 + l4 * 16) ^ swz)];
  const char* ap10 = &Ash[0][(rh * 32 + 16 + l15) * 512 + ((     l4 * 16) ^ swz)];
  const char* ap11 = &Ash[0][(rh * 32 + 16 + l15) * 512 + ((64 + l4 * 16) ^ swz)];

  // stage chunk at src -> dbuf (32 segs of 1 KB, 8 per wave)
  auto stage = [&](const char* s, char* dbuf) {
#pragma unroll
    for (int i2 = 0; i2 < 8; ++i2) {
      const int seg = i2 * 4 + w;
      async16(s + seg * 1024 + lane * 16, dbuf + seg * 1024);
    }
  };
  // QK^T of one chunk: 64 MFMA/wave; A via precomputed addrs + immediates.
  // acc init = C0f (exp bias baked into the matmul's C operand).
  auto qk = [&](f32x4 (&acc)[2][4], const int OFS) {
#pragma unroll
    for (int i2 = 0; i2 < 2; ++i2)
#pragma unroll
      for (int j = 0; j < 4; ++j) acc[i2][j] = f32x4{C0f, C0f, C0f, C0f};
    __builtin_amdgcn_s_setprio(1);
#pragma unroll
    for (int ks = 0; ks < 8; ++ks) {
      const int ko = OFS + (ks >> 1) * 128;
      const bf16x8 af0 = *(const bf16x8*)(((ks & 1) ? ap01 : ap00) + ko);
      const bf16x8 af1 = *(const bf16x8*)(((ks & 1) ? ap11 : ap10) + ko);
#pragma unroll
      for (int nt = 0; nt < 4; ++nt)
        acc[0][nt] = __builtin_amdgcn_mfma_f32_16x16x32_bf16(
            af0, bfr[nt][ks], acc[0][nt], 0, 0, 0);
#pragma unroll
      for (int nt = 0; nt < 4; ++nt)
        acc[1][nt] = __builtin_amdgcn_mfma_f32_16x16x32_bf16(
            af1, bfr[nt][ks], acc[1][nt], 0, 0, 0);
    }
    __builtin_amdgcn_s_setprio(0);
  };
  // exp2 + pack + PV (wave-local; acc reg layout IS the PV B-frag layout)
  auto pv = [&](const f32x4 (&acc)[2][4], unsigned la, unsigned lb2) {
    union { bf16x8 v; unsigned u[4]; } lf;
    lf.u[0] = oh2(la, l15);        lf.u[1] = oh2(la >> 16, l15);
    lf.u[2] = oh2(lb2, l15);       lf.u[3] = oh2(lb2 >> 16, l15);
#pragma unroll
    for (int nt = 0; nt < 4; ++nt) {
      const f32x4 a0 = acc[0][nt], a1 = acc[1][nt];
      float p0 = __builtin_amdgcn_exp2f(a0[0]);
      float p1 = __builtin_amdgcn_exp2f(a0[1]);
      float p2 = __builtin_amdgcn_exp2f(a0[2]);
      float p3 = __builtin_amdgcn_exp2f(a0[3]);
      float p4 = __builtin_amdgcn_exp2f(a1[0]);
      float p5 = __builtin_amdgcn_exp2f(a1[1]);
      float p6 = __builtin_amdgcn_exp2f(a1[2]);
      float p7 = __builtin_amdgcn_exp2f(a1[3]);
      union { bf16x8 v; unsigned u[4]; } pf;
      pf.u[0] = cvtpk(p0, p1); pf.u[1] = cvtpk(p2, p3);
      pf.u[2] = cvtpk(p4, p5); pf.u[3] = cvtpk(p6, p7);
      pacc[nt] = __builtin_amdgcn_mfma_f32_16x16x32_bf16(lf.v, pf.v, pacc[nt], 0, 0, 0);
    }
  };

  f32x4 acc[2][4];
  const unsigned char* lbp = lab8 + b * RTOT + rs * RPB + rh * 32 + l4 * 4;
  const char* Acur = Asrc + 2 * (RR * 512);   // global source of chunk 2 (next to stage)

  // prologue: load labels(0); stage(0)->buf0; drain; stage(1)->buf1; qk(0)
  unsigned la_p = *(const unsigned*)lbp;      // labels(0), old by first use
  unsigned lb_p = *(const unsigned*)(lbp + 16);
  lbp += RR;
  stage(Asrc, &Ash[0][0]);
  __syncthreads();
  stage(Asrc + RR * 512, &Ash[1][0]);
  qk(acc, 0);

#pragma unroll 1
  for (int i = 0; i < 11; ++i) {
    {   // step: chunk c=1+2i (odd, buf1); labels(c) loaded AFTER barrier
      __syncthreads();                   // all pending vmem >= 1 chunk old
      const unsigned la_n = *(const unsigned*)lbp;         // labels(c)
      const unsigned lb_n = *(const unsigned*)(lbp + 16);
      lbp += RR;
      stage(Acur, &Ash[0][0]); Acur += RR * 512;
      pv(acc, la_p, lb_p);               // chunk c-1 (regs only)
      qk(acc, 32768);                    // chunk c from buf1
      la_p = la_n; lb_p = lb_n;
    }
    {   // step: chunk c=2+2i (even, buf0)
      __syncthreads();
      const unsigned la_n = *(const unsigned*)lbp;         // labels(c)
      const unsigned lb_n = *(const unsigned*)(lbp + 16);
      lbp += RR;
      stage(Acur, &Ash[1][0]); Acur += RR * 512;
      pv(acc, la_p, lb_p);               // chunk c-1
      qk(acc, 0);                        // chunk c from buf0
      la_p = la_n; lb_p = lb_n;
    }
  }
  {   // chunk 23 (odd, buf1): no stage; then final pv(23)
    __syncthreads();                     // drain DMA(23) (1 chunk old)
    const unsigned la_n = *(const unsigned*)lbp;   // labels(23)
    const unsigned lb_n = *(const unsigned*)(lbp + 16);
    pv(acc, la_p, lb_p);                 // chunk 22
    qk(acc, 32768);                      // chunk 23
    pv(acc, la_n, lb_n);                 // chunk 23 (one-time load latency, tail only)
  }

  // ---- cross-wave reduction of rh partials (once), then global write ----
  __syncthreads();                       // everyone done with Ash (no DMA pending)
  float* sc = (float*)&Ash[0][0];        // 8 KB scratch
  if (rh == 1) {
#pragma unroll
    for (int nt = 0; nt < 4; ++nt)
      *(f32x4*)&sc[((th * 64 + lane) * 4 + nt) * 4] = pacc[nt];
  }
  __syncthreads();
  if (rh == 0) {
#pragma unroll
    for (int nt = 0; nt < 4; ++nt) {
      pacc[nt] += *(const f32x4*)&sc[((th * 64 + lane) * 4 + nt) * 4];
      const int t = th * 64 + nt * 16 + l15;
      const size_t o = (((size_t)(rs * B_ + b)) * HW + (size_t)tb * TT + t) * 16 + l4 * 4;
      *(f32x4*)&pred[o] = pacc[nt];
    }
  }
}

// ---------------- kernel 3: per-pixel loss terms + block reduce ----------------
__global__ __launch_bounds__(256) void k_epi(const float* __restrict__ pred,
                                             const int* __restrict__ tl,
                                             float* __restrict__ red) {
  const int idx = blockIdx.x * 256 + threadIdx.x;   // < 8192
  const int b = idx >> 12, t = idx & 4095;
  union { f32x4 v[3]; float f[12]; } S;
  S.v[0] = f32x4{0.f, 0.f, 0.f, 0.f};
  S.v[1] = f32x4{0.f, 0.f, 0.f, 0.f};
  S.v[2] = f32x4{0.f, 0.f, 0.f, 0.f};
#pragma unroll
  for (int r = 0; r < RS; ++r) {
    const f32x4* p = (const f32x4*)&pred[(((size_t)(r * B_ + b)) * HW + t) * 16];
    S.v[0] += p[0]; S.v[1] += p[1]; S.v[2] += p[2];
  }
  float T = 0.f;
#pragma unroll
  for (int d = 0; d < DCLS; ++d) T += S.f[d];
  const float inv = 1.f / T;
  const int lb = tl[idx];
  float se = 0.f, zt = 0.f;
#pragma unroll
  for (int d = 0; d < DCLS; ++d) {
    const float z = S.f[d] * inv;      // pred prob in [0,1]
    se += __expf(z);
    if (d == lb) zt = z;
  }
  const float logpt = zt - __logf(se);
  const float pt = __expf(zt) / se;
  const float focal = sqrtf(fmaxf(1.f - pt, 0.f));   // gamma = 0.5

  float lp = logpt, fo = focal;
#pragma unroll
  for (int off = 32; off; off >>= 1) {
    lp += __shfl_down(lp, off);
    fo += __shfl_down(fo, off);
  }
  __shared__ float rb_[8];
  const int lane = threadIdx.x & 63, wv = threadIdx.x >> 6;
  if (lane == 0) { rb_[wv] = lp; rb_[4 + wv] = fo; }
  __syncthreads();
  if (threadIdx.x == 0) {
    red[blockIdx.x * 2 + 0] = rb_[0] + rb_[1] + rb_[2] + rb_[3];
    red[blockIdx.x * 2 + 1] = rb_[4] + rb_[5] + rb_[6] + rb_[7];
  }
}

// ---------------- kernel 4: final scalar ----------------
__global__ void k_fin(const float* __restrict__ red, float* __restrict__ out) {
  const int tid = threadIdx.x;   // 64
  float lp = 0.f, fo = 0.f;
  if (tid < 32) { lp = red[tid * 2]; fo = red[tid * 2 + 1]; }
#pragma unroll
  for (int off = 16; off; off >>= 1) {
    lp += __shfl_down(lp, off);
    fo += __shfl_down(fo, off);
  }
  if (tid == 0) {
    const float ce = -lp / (float)NPIX;       // ce = -mean(log_pt)
    out[0] = ce * (fo / (float)NPIX);         // loss = ce * mean(focal)
  }
}

extern "C" void kernel_launch(void* const* d_in, const int* in_sizes, int n_in,
                              void* d_out, int out_size, void* d_ws, size_t ws_size,
                              hipStream_t stream)
{
  const float* ref  = (const float*)d_in[0];
  const float* tgt  = (const float*)d_in[1];
  const float* rl   = (const float*)d_in[2];
  const int*   tlab = (const int*)d_in[3];
  float* out = (float*)d_out;

  char* ws = (char*)d_ws;
  char* refb = ws;                                    // 32768 rows * 512 B = 16 MB (ref + tgt)
  char* tgtb = ws + (size_t)24576 * 512;              // tgt rows start at 24576
  unsigned char* lab8 = (unsigned char*)(ws + 16777216);          // 24 KB (pad 32 KB)
  float* pred = (float*)(ws + 16777216 + 32768);                  // 4 MB (RS*B*HW*16 f32)
  float* red  = (float*)(ws + 16777216 + 32768 + 4194304);        // 256 B

  k_pre<<<608, 256, 0, stream>>>(ref, tgt, rl, refb, lab8);
  k_main<<<512, 256, 0, stream>>>(refb, tgtb, lab8, pred);
  k_epi<<<32, 256, 0, stream>>>(pred, tlab, red);
  k_fin<<<1, 64, 0, stream>>>(red, out);
}

// Round 13
// 59.137 us; speedup vs baseline: 1.3380x; 1.0107x over previous
//
#include <hip/hip_runtime.h>
#include <hip/hip_bf16.h>
#include <stdint.h>
#include <stddef.h>

// Problem constants
#define B_    2
#define NREF  3
#define FDIM  256
#define HW    4096
#define DCLS  10
#define RTOT  12288          // NREF*HW reference pixels per batch
#define TT    128            // target pixels per block (4 waves)
#define RR    64             // reference pixels per chunk
#define RS    8              // r-axis split across blocks
#define RPB   1536           // RTOT/RS
#define NCH   24             // RPB/RR
#define NPIX  8192           // B_*HW
#define LOG2E 1.44269504f
#define C0f   (-144.269504f)  // -100*LOG2E; QK acc init so acc = sim*log2e - 100*log2e

typedef __attribute__((ext_vector_type(8))) short bf16x8;
typedef __attribute__((ext_vector_type(4))) float f32x4;
typedef __attribute__((ext_vector_type(4))) unsigned int u32x4;

__device__ __forceinline__ unsigned short f2bf(float x) {
  union { float f; unsigned u; } v; v.f = x;
  unsigned r = v.u + 0x7fffu + ((v.u >> 16) & 1u);   // RNE
  return (unsigned short)(r >> 16);
}
__device__ __forceinline__ unsigned pk2(float a, float b) {
  return (unsigned)f2bf(a) | ((unsigned)f2bf(b) << 16);
}
// single-instruction packed f32->bf16 (RNE), gfx950
__device__ __forceinline__ unsigned cvtpk(float a, float b) {
  unsigned r;
  asm("v_cvt_pk_bf16_f32 %0, %1, %2" : "=v"(r) : "v"(a), "v"(b));
  return r;
}
// async global->LDS, 16B per lane; LDS dest is wave-uniform base + lane*16
__device__ __forceinline__ void async16(const void* g, void* l) {
  __builtin_amdgcn_global_load_lds(
      (const __attribute__((address_space(1))) void*)g,
      (__attribute__((address_space(3))) void*)l, 16, 0, 0);
}
// one-hot pair: low/high 16-bit bf16 1.0 where label byte matches d=l15
__device__ __forceinline__ unsigned oh2(unsigned word, int d) {
  return ((word & 255u) == (unsigned)d ? 0x3F80u : 0u) |
         (((word >> 8) & 255u) == (unsigned)d ? 0x3F800000u : 0u);
}

// ---------------- kernel 1: fused prep (transpose+convert) + label extract ----------------
// blocks [0,512): ref/tgt -> bf16 rows of 512B with XOR swizzle baked per row.
// Each block: 64 rows x 4 quarter-rows (256 thr); 512 blocks cover all 32768 rows.
// blocks [512,608): one-hot -> u8 labels.
__global__ __launch_bounds__(256) void k_pre(const float* __restrict__ ref,
                                             const float* __restrict__ tgt,
                                             const float* __restrict__ rl,
                                             char* __restrict__ outb,
                                             unsigned char* __restrict__ lab8) {
  const int tid = threadIdx.x;
  if (blockIdx.x < 512) {
    const int row = blockIdx.x * 64 + (tid & 63);     // row 0..32767 (lane-coalesced)
    const int q = tid >> 6;                           // quarter 0..3
    const float* src;
    float scl;
    if (row < B_ * RTOT) {
      const int b = row / RTOT, rr2 = row % RTOT;
      src = ref + ((size_t)(b * NREF + (rr2 >> 12)) * FDIM) * HW + (rr2 & 4095);
      scl = LOG2E;
    } else {
      const int r2 = row - B_ * RTOT;
      src = tgt + ((size_t)(r2 >> 12) * FDIM) * HW + (r2 & 4095);
      scl = 1.0f;
    }
    char* dst = outb + (size_t)row * 512;
    const int sw = (row & 7) << 4;
#pragma unroll
    for (int ci = 0; ci < 4; ++ci) {
      const int c16 = q * 4 + ci;
      float v[8];
#pragma unroll
      for (int j = 0; j < 8; ++j) v[j] = src[(size_t)(c16 * 8 + j) * HW] * scl;
      u32x4 u;
      u[0] = pk2(v[0], v[1]); u[1] = pk2(v[2], v[3]);
      u[2] = pk2(v[4], v[5]); u[3] = pk2(v[6], v[7]);
      *(u32x4*)(dst + ((c16 * 16) ^ sw)) = u;
    }
  } else {
    const int idx = (blockIdx.x - 512) * 256 + tid;   // < 24576
    if (idx >= B_ * RTOT) return;
    const int b = idx / RTOT, r = idx % RTOT;
    const float* p = rl + ((size_t)((b * NREF + (r >> 12)) * DCLS)) * HW + (r & 4095);
    int v = 0;
#pragma unroll
    for (int d = 1; d < DCLS; ++d)
      if (p[(size_t)d * HW] > 0.5f) v = d;
    lab8[idx] = (unsigned char)v;
  }
}

// ---------------- kernel 2: fused QK-softmax-PV (dual accumulator pipeline) ----------------
// grid = RS(8) * 32(tblocks) * B_(2) = 512 blocks of 256 threads, 2 blocks/CU.
// Chunk c goes to accA (even) / accB (odd). Per step: barrier; labels(c);
// stage(c+1); pv(other acc = chunk c-1) || qk(this acc = chunk c). The two acc
// sets are disjoint registers -> NO WAR between pv and qk -> compiler can
// interleave pv's exp/cvtpk/PV-MFMA into qk's ds_read shadows and MFMA stream
// (round-12's single-acc version serialized the VALU and MFMA phases).
// Register budget: bfr 128 + accA 32 + accB 32 + pacc 16 + temps ~25 ≈ 233 < 256.
__global__ __launch_bounds__(256, 2) void k_main(const char* __restrict__ refb,
                                                 const char* __restrict__ tgtb,
                                                 const unsigned char* __restrict__ lab8,
                                                 float* __restrict__ pred) {
  __shared__ __align__(16) char Ash[2][RR * 512];   // double-buffered ref chunk, 64 KB

  const int tid = threadIdx.x;
  const int lane = tid & 63;
  const int w = tid >> 6;                // wave 0..3
  const int l15 = lane & 15, l4 = lane >> 4;
  const int rh = w >> 1, th = w & 1;     // wave sub-tile: 32r x 64t
  const int swz = (l15 & 7) << 4;

  const int bid = blockIdx.x;
  const int rs = bid & 7;
  const int tb = (bid >> 3) & 31;
  const int b  = bid >> 8;

  // ---- B fragments in registers: wave's 64 t x full K=256 (128 VGPR) ----
  bf16x8 bfr[4][8];
  {
    const char* base = tgtb + ((size_t)(b * HW + tb * TT + th * 64)) * 512;
#pragma unroll
    for (int nt = 0; nt < 4; ++nt) {
      const char* rp = base + (size_t)((nt * 16 + l15) * 512);
#pragma unroll
      for (int ks = 0; ks < 8; ++ks)
        bfr[nt][ks] = *(const bf16x8*)(rp + ((ks * 64 + l4 * 16) ^ swz));
    }
  }

  f32x4 pacc[4];
#pragma unroll
  for (int i = 0; i < 4; ++i) pacc[i] = f32x4{0.f, 0.f, 0.f, 0.f};

  const char* Asrc = refb + ((size_t)(b * RTOT + rs * RPB)) * 512;

  // precomputed A-read base pointers (buf0); buf1 reached via +32768 immediate
  const char* ap00 = &Ash[0][(rh * 32 +  0 + l15) * 512 + ((     l4 * 16) ^ swz)];
  const char* ap01 = &Ash[0][(rh * 32 +  0 + l15) * 512 + ((64 + l4 * 16) ^ swz)];
  const char* ap10 = &Ash[0][(rh * 32 + 16 + l15) * 512 + ((     l4 * 16) ^ swz)];
  const char* ap11 = &Ash[0][(rh * 32 + 16 + l15) * 512 + ((64 + l4 * 16) ^ swz)];

  // stage chunk at src -> dbuf (32 segs of 1 KB, 8 per wave)
  auto stage = [&](const char* s, char* dbuf) {
#pragma unroll
    for (int i2 = 0; i2 < 8; ++i2) {
      const int seg = i2 * 4 + w;
      async16(s + seg * 1024 + lane * 16, dbuf + seg * 1024);
    }
  };
  // QK^T of one chunk into the given acc set: 64 MFMA/wave; acc init = C0f.
  auto qk = [&](f32x4 (&acc)[2][4], const int OFS) {
#pragma unroll
    for (int i2 = 0; i2 < 2; ++i2)
#pragma unroll
      for (int j = 0; j < 4; ++j) acc[i2][j] = f32x4{C0f, C0f, C0f, C0f};
    __builtin_amdgcn_s_setprio(1);
#pragma unroll
    for (int ks = 0; ks < 8; ++ks) {
      const int ko = OFS + (ks >> 1) * 128;
      const bf16x8 af0 = *(const bf16x8*)(((ks & 1) ? ap01 : ap00) + ko);
      const bf16x8 af1 = *(const bf16x8*)(((ks & 1) ? ap11 : ap10) + ko);
#pragma unroll
      for (int nt = 0; nt < 4; ++nt)
        acc[0][nt] = __builtin_amdgcn_mfma_f32_16x16x32_bf16(
            af0, bfr[nt][ks], acc[0][nt], 0, 0, 0);
#pragma unroll
      for (int nt = 0; nt < 4; ++nt)
        acc[1][nt] = __builtin_amdgcn_mfma_f32_16x16x32_bf16(
            af1, bfr[nt][ks], acc[1][nt], 0, 0, 0);
    }
    __builtin_amdgcn_s_setprio(0);
  };
  // exp2 + pack + PV from the given acc set (reads only; disjoint from qk's set)
  auto pv = [&](const f32x4 (&acc)[2][4], unsigned la, unsigned lb2) {
    union { bf16x8 v; unsigned u[4]; } lf;
    lf.u[0] = oh2(la, l15);        lf.u[1] = oh2(la >> 16, l15);
    lf.u[2] = oh2(lb2, l15);       lf.u[3] = oh2(lb2 >> 16, l15);
#pragma unroll
    for (int nt = 0; nt < 4; ++nt) {
      const f32x4 a0 = acc[0][nt], a1 = acc[1][nt];
      float p0 = __builtin_amdgcn_exp2f(a0[0]);
      float p1 = __builtin_amdgcn_exp2f(a0[1]);
      float p2 = __builtin_amdgcn_exp2f(a0[2]);
      float p3 = __builtin_amdgcn_exp2f(a0[3]);
      float p4 = __builtin_amdgcn_exp2f(a1[0]);
      float p5 = __builtin_amdgcn_exp2f(a1[1]);
      float p6 = __builtin_amdgcn_exp2f(a1[2]);
      float p7 = __builtin_amdgcn_exp2f(a1[3]);
      union { bf16x8 v; unsigned u[4]; } pf;
      pf.u[0] = cvtpk(p0, p1); pf.u[1] = cvtpk(p2, p3);
      pf.u[2] = cvtpk(p4, p5); pf.u[3] = cvtpk(p6, p7);
      pacc[nt] = __builtin_amdgcn_mfma_f32_16x16x32_bf16(lf.v, pf.v, pacc[nt], 0, 0, 0);
    }
  };

  f32x4 accA[2][4], accB[2][4];   // dual acc sets, statically indexed (rule #20)
  const unsigned char* lbp = lab8 + b * RTOT + rs * RPB + rh * 32 + l4 * 4;
  const char* Acur = Asrc + 2 * (RR * 512);   // global source of chunk 2 (next to stage)

  // prologue: labels(0); stage(0)->buf0; drain; stage(1)->buf1; qk(0)->accA
  unsigned la_p = *(const unsigned*)lbp;      // labels(0)
  unsigned lb_p = *(const unsigned*)(lbp + 16);
  lbp += RR;
  stage(Asrc, &Ash[0][0]);
  __syncthreads();
  stage(Asrc + RR * 512, &Ash[1][0]);
  qk(accA, 0);

#pragma unroll 1
  for (int i = 0; i < 11; ++i) {
    {   // step: chunk c=1+2i (odd, buf1) -> accB; pv(accA = chunk c-1)
      __syncthreads();                   // all pending vmem >= 1 chunk old
      const unsigned la_n = *(const unsigned*)lbp;         // labels(c)
      const unsigned lb_n = *(const unsigned*)(lbp + 16);
      lbp += RR;
      stage(Acur, &Ash[0][0]); Acur += RR * 512;
      pv(accA, la_p, lb_p);              // disjoint regs from qk(accB) below
      qk(accB, 32768);
      la_p = la_n; lb_p = lb_n;
    }
    {   // step: chunk c=2+2i (even, buf0) -> accA; pv(accB = chunk c-1)
      __syncthreads();
      const unsigned la_n = *(const unsigned*)lbp;         // labels(c)
      const unsigned lb_n = *(const unsigned*)(lbp + 16);
      lbp += RR;
      stage(Acur, &Ash[1][0]); Acur += RR * 512;
      pv(accB, la_p, lb_p);
      qk(accA, 0);
      la_p = la_n; lb_p = lb_n;
    }
  }
  {   // chunk 23 (odd, buf1) -> accB: no stage; then final pv(accB)
    __syncthreads();                     // drain DMA(23) (1 chunk old)
    const unsigned la_n = *(const unsigned*)lbp;   // labels(23)
    const unsigned lb_n = *(const unsigned*)(lbp + 16);
    pv(accA, la_p, lb_p);                // chunk 22
    qk(accB, 32768);                     // chunk 23
    pv(accB, la_n, lb_n);                // chunk 23
  }

  // ---- cross-wave reduction of rh partials (once), then global write ----
  __syncthreads();                       // everyone done with Ash (no DMA pending)
  float* sc = (float*)&Ash[0][0];        // 8 KB scratch
  if (rh == 1) {
#pragma unroll
    for (int nt = 0; nt < 4; ++nt)
      *(f32x4*)&sc[((th * 64 + lane) * 4 + nt) * 4] = pacc[nt];
  }
  __syncthreads();
  if (rh == 0) {
#pragma unroll
    for (int nt = 0; nt < 4; ++nt) {
      pacc[nt] += *(const f32x4*)&sc[((th * 64 + lane) * 4 + nt) * 4];
      const int t = th * 64 + nt * 16 + l15;
      const size_t o = (((size_t)(rs * B_ + b)) * HW + (size_t)tb * TT + t) * 16 + l4 * 4;
      *(f32x4*)&pred[o] = pacc[nt];
    }
  }
}

// ---------------- kernel 3: per-pixel loss terms + block reduce ----------------
__global__ __launch_bounds__(256) void k_epi(const float* __restrict__ pred,
                                             const int* __restrict__ tl,
                                             float* __restrict__ red) {
  const int idx = blockIdx.x * 256 + threadIdx.x;   // < 8192
  const int b = idx >> 12, t = idx & 4095;
  union { f32x4 v[3]; float f[12]; } S;
  S.v[0] = f32x4{0.f, 0.f, 0.f, 0.f};
  S.v[1] = f32x4{0.f, 0.f, 0.f, 0.f};
  S.v[2] = f32x4{0.f, 0.f, 0.f, 0.f};
#pragma unroll
  for (int r = 0; r < RS; ++r) {
    const f32x4* p = (const f32x4*)&pred[(((size_t)(r * B_ + b)) * HW + t) * 16];
    S.v[0] += p[0]; S.v[1] += p[1]; S.v[2] += p[2];
  }
  float T = 0.f;
#pragma unroll
  for (int d = 0; d < DCLS; ++d) T += S.f[d];
  const float inv = 1.f / T;
  const int lb = tl[idx];
  float se = 0.f, zt = 0.f;
#pragma unroll
  for (int d = 0; d < DCLS; ++d) {
    const float z = S.f[d] * inv;      // pred prob in [0,1]
    se += __expf(z);
    if (d == lb) zt = z;
  }
  const float logpt = zt - __logf(se);
  const float pt = __expf(zt) / se;
  const float focal = sqrtf(fmaxf(1.f - pt, 0.f));   // gamma = 0.5

  float lp = logpt, fo = focal;
#pragma unroll
  for (int off = 32; off; off >>= 1) {
    lp += __shfl_down(lp, off);
    fo += __shfl_down(fo, off);
  }
  __shared__ float rb_[8];
  const int lane = threadIdx.x & 63, wv = threadIdx.x >> 6;
  if (lane == 0) { rb_[wv] = lp; rb_[4 + wv] = fo; }
  __syncthreads();
  if (threadIdx.x == 0) {
    red[blockIdx.x * 2 + 0] = rb_[0] + rb_[1] + rb_[2] + rb_[3];
    red[blockIdx.x * 2 + 1] = rb_[4] + rb_[5] + rb_[6] + rb_[7];
  }
}

// ---------------- kernel 4: final scalar ----------------
__global__ void k_fin(const float* __restrict__ red, float* __restrict__ out) {
  const int tid = threadIdx.x;   // 64
  float lp = 0.f, fo = 0.f;
  if (tid < 32) { lp = red[tid * 2]; fo = red[tid * 2 + 1]; }
#pragma unroll
  for (int off = 16; off; off >>= 1) {
    lp += __shfl_down(lp, off);
    fo += __shfl_down(fo, off);
  }
  if (tid == 0) {
    const float ce = -lp / (float)NPIX;       // ce = -mean(log_pt)
    out[0] = ce * (fo / (float)NPIX);         // loss = ce * mean(focal)
  }
}

extern "C" void kernel_launch(void* const* d_in, const int* in_sizes, int n_in,
                              void* d_out, int out_size, void* d_ws, size_t ws_size,
                              hipStream_t stream)
{
  const float* ref  = (const float*)d_in[0];
  const float* tgt  = (const float*)d_in[1];
  const float* rl   = (const float*)d_in[2];
  const int*   tlab = (const int*)d_in[3];
  float* out = (float*)d_out;

  char* ws = (char*)d_ws;
  char* refb = ws;                                    // 32768 rows * 512 B = 16 MB (ref + tgt)
  char* tgtb = ws + (size_t)24576 * 512;              // tgt rows start at 24576
  unsigned char* lab8 = (unsigned char*)(ws + 16777216);          // 24 KB (pad 32 KB)
  float* pred = (float*)(ws + 16777216 + 32768);                  // 4 MB (RS*B*HW*16 f32)
  float* red  = (float*)(ws + 16777216 + 32768 + 4194304);        // 256 B

  k_pre<<<608, 256, 0, stream>>>(ref, tgt, rl, refb, lab8);
  k_main<<<512, 256, 0, stream>>>(refb, tgtb, lab8, pred);
  k_epi<<<32, 256, 0, stream>>>(pred, tlab, red);
  k_fin<<<1, 64, 0, stream>>>(red, out);
}